// Round 10
// baseline (882.474 us; speedup 1.0000x reference)
//
#include <hip/hip_runtime.h>
#include <math.h>

// Graph-diffusion, 10 steps of edge-scatter + node update.
//
// R9 post-mortem: k_step is gather-bound (splits- and TPB-insensitive): each
// wave's 64 random cur[src] addresses -> ~64 serialized TA transactions per
// gather instruction. R3's WRITE_SIZE (224.6 = 199.6 + E*4B rank) proves the
// FULL tier ran => ws_size >= 78MB.
// R10: 2D (dst-bin x src-chunk) bucketing, 4096 nodes each (625 buckets):
//   k_hist : per-block LDS histogram (2.5KB -> ~8 blocks/CU), exact counts
//   scan   : 3-kernel exclusive scan of ph[625*256]
//   k_place: per-block LDS cursors -> exact slot; 625 open write regions
//            stay L2-resident (write amp ~1.3x, vs R4 k_part's 3.5x @ 3128)
//   k_step : one block per bucket: src-window (16KB) staged in LDS once
//            (coalesced), per-edge = LDS read + LDS atomic -> ZERO gathers;
//            partial per (src-chunk) written non-atomically
//   k_reduce: sum nchunk partials + fused scale/bias/surv/clip.

#define PB       256     // hist/place grid (must match between the two)
#define BT       256     // TPB everywhere in build
#define SH2      12
#define B2       4096    // nodes per dst-bin and per src-chunk
#define MAXB     1024    // max 2D buckets supported
#define STEP_TPB 256

__global__ void k_detect(const unsigned long long* ei, int* flag) {
    if (blockIdx.x == 0 && threadIdx.x == 0) {
        // int64 indices (<2^17) have zero high words; int32 data read as u64
        // carries a random index in the high word (all-64-zero ~ never).
        int is64 = 1;
        for (int k = 0; k < 64; ++k)
            if ((ei[k] >> 32) != 0ULL) { is64 = 0; break; }
        *flag = is64;
    }
}

__global__ void k_scales(const float* __restrict__ time_decay,
                         const float* __restrict__ edge_weight,
                         float* __restrict__ step_scale, int num_steps) {
    int i = threadIdx.x;
    if (i < num_steps) {
        float td = time_decay[i];
        step_scale[i] = edge_weight[i] * expf(-td * td);
    }
}

__global__ void k_init(const float* __restrict__ x, float* __restrict__ cur0,
                       float* __restrict__ surv, int n) {
    int i = blockIdx.x * blockDim.x + threadIdx.x;
    if (i < n) {
        float v = x[i];
        cur0[i] = v;
        surv[i] = 1.0f - v;
    }
}

// Per-block LDS histogram over 2D buckets; write bucket-major ph[b*PB+bid].
__global__ void k_hist(const void* __restrict__ ei_raw, const int* __restrict__ flag,
                       unsigned int* __restrict__ ph, int E, int nbuckets, int nchunk) {
    __shared__ unsigned int h[MAXB];
    const int bid = blockIdx.x, t = threadIdx.x;
    for (int i = t; i < nbuckets; i += BT) h[i] = 0u;
    __syncthreads();
    const int chunk = (E + PB - 1) / PB;
    const int beg = bid * chunk;
    const int end = min(E, beg + chunk);
    if (*flag) {
        const long long* s = (const long long*)ei_raw;
        for (int e = beg + t; e < end; e += BT) {
            int src = (int)s[e], dst = (int)s[e + E];
            atomicAdd(&h[(dst >> SH2) * nchunk + (src >> SH2)], 1u);
        }
    } else {
        const int* s = (const int*)ei_raw;
        for (int e = beg + t; e < end; e += BT) {
            int src = s[e], dst = s[e + E];
            atomicAdd(&h[(dst >> SH2) * nchunk + (src >> SH2)], 1u);
        }
    }
    __syncthreads();
    for (int i = t; i < nbuckets; i += BT)
        ph[(size_t)i * PB + bid] = h[i];
}

// 3-kernel exclusive scan over ntotal = nbuckets*PB entries.
__global__ void k_scan1(unsigned int* __restrict__ arr, unsigned int* __restrict__ partials,
                        int ntotal) {
    __shared__ unsigned int lds[1024];
    const int t = threadIdx.x;
    int i = blockIdx.x * 1024 + t;
    unsigned int v = (i < ntotal) ? arr[i] : 0u;
    lds[t] = v;
    __syncthreads();
    for (int off = 1; off < 1024; off <<= 1) {
        unsigned int a = (t >= off) ? lds[t - off] : 0u;
        __syncthreads();
        lds[t] += a;
        __syncthreads();
    }
    if (i < ntotal) arr[i] = lds[t] - v;
    if (t == 0) partials[blockIdx.x] = lds[1023];
}

__global__ void k_scan2(unsigned int* __restrict__ partials, int nb) {
    __shared__ unsigned int lds[1024];
    const int t = threadIdx.x;
    unsigned int v = (t < nb) ? partials[t] : 0u;
    lds[t] = v;
    __syncthreads();
    for (int off = 1; off < 1024; off <<= 1) {
        unsigned int a = (t >= off) ? lds[t - off] : 0u;
        __syncthreads();
        lds[t] += a;
        __syncthreads();
    }
    if (t < nb) partials[t] = lds[t] - v;
}

__global__ void k_scan3(unsigned int* __restrict__ arr, const unsigned int* __restrict__ partials,
                        int ntotal) {
    int i = blockIdx.x * 1024 + threadIdx.x;
    if (i < ntotal) arr[i] += partials[blockIdx.x];
}

// Place each edge at its exact slot via per-block LDS cursors (same chunking
// as k_hist). Payload: key = src_local | dst_local<<SH2, prob f32.
__global__ void k_place(const void* __restrict__ ei_raw, const int* __restrict__ flag,
                        const float* __restrict__ probs, const unsigned int* __restrict__ ph,
                        float2* __restrict__ sorted, int E, int nbuckets, int nchunk) {
    __shared__ unsigned int cur[MAXB];
    const int bid = blockIdx.x, t = threadIdx.x;
    for (int i = t; i < nbuckets; i += BT)
        cur[i] = ph[(size_t)i * PB + bid];
    __syncthreads();
    const int chunk = (E + PB - 1) / PB;
    const int beg = bid * chunk;
    const int end = min(E, beg + chunk);
    const int is64 = *flag;
    for (int e = beg + t; e < end; e += BT) {
        int src, dst;
        if (is64) {
            const long long* s = (const long long*)ei_raw;
            src = (int)s[e]; dst = (int)s[e + E];
        } else {
            const int* s = (const int*)ei_raw;
            src = s[e]; dst = s[e + E];
        }
        int b = (dst >> SH2) * nchunk + (src >> SH2);
        unsigned int pos = atomicAdd(&cur[b], 1u);
        unsigned int key = (unsigned int)(src & (B2 - 1)) |
                           ((unsigned int)(dst & (B2 - 1)) << SH2);
        sorted[pos] = make_float2(__uint_as_float(key), probs[e]);
    }
}

// One block per bucket (d = dst-bin, c = src-chunk): stage cur window in LDS,
// stream segment (LDS read + LDS atomic, zero gathers), write partial.
__global__ void __launch_bounds__(STEP_TPB)
k_step(const float2* __restrict__ sorted, const unsigned int* __restrict__ ph,
       const float* __restrict__ cur_in, float* __restrict__ part,
       int pstride, int nbuckets, int nchunk, int n, int E) {
    __shared__ float win[B2];
    __shared__ float acc[B2];
    const int bid = blockIdx.x, t = threadIdx.x;
    const int d = bid / nchunk, c = bid - d * nchunk;
    const int cbase = c << SH2;
    for (int i = t; i < B2; i += STEP_TPB) {
        acc[i] = 0.0f;
        int g = cbase + i;
        win[i] = (g < n) ? cur_in[g] : 0.0f;
    }
    __syncthreads();
    unsigned int s0 = ph[(size_t)bid * PB];
    unsigned int s1 = (bid + 1 < nbuckets) ? ph[(size_t)(bid + 1) * PB] : (unsigned int)E;
    for (unsigned int j = s0 + t; j < s1; j += STEP_TPB) {
        float2 kp = sorted[j];
        unsigned int k = __float_as_uint(kp.x);
        float m = win[k & (B2 - 1)] * kp.y;
        atomicAdd(&acc[(k >> SH2) & (B2 - 1)], m);
    }
    __syncthreads();
    float* row = part + (size_t)c * pstride + ((size_t)d << SH2);
    for (int i = t; i < B2; i += STEP_TPB)
        row[i] = acc[i];
}

// Sum nchunk partials + fused scale/bias/surv/clip.
__global__ void k_reduce(const float* __restrict__ part, int pstride, int nchunk,
                         float* __restrict__ cur_out, float* __restrict__ surv,
                         const float* __restrict__ step_scale, const float* __restrict__ bias_p,
                         float* __restrict__ out, int step, int n, int last) {
    int i = blockIdx.x * blockDim.x + threadIdx.x;
    if (i >= n) return;
    float c = 0.0f;
    for (int s = 0; s < nchunk; ++s) c += part[(size_t)s * pstride + i];
    c = c * step_scale[step] + bias_p[0];
    if (!last) cur_out[i] = c;
    float sv = surv[i] * (1.0f - c);
    surv[i] = sv;
    if (last) out[i] = fminf(fmaxf(1.0f - sv, 0.0f), 1.0f);
}

// --- minimal fallback (ws too small / shape unsupported; not expected) ---
__global__ void k_init0(const float* __restrict__ x, float* __restrict__ cur,
                        float* __restrict__ surv, float* __restrict__ acc, int n) {
    int i = blockIdx.x * blockDim.x + threadIdx.x;
    if (i < n) {
        float v = x[i];
        cur[i] = v; surv[i] = 1.0f - v; acc[i] = 0.0f;
    }
}

__global__ void k_edge_raw(const void* __restrict__ ei_raw, const int* __restrict__ flag,
                           const float* __restrict__ probs, const float* __restrict__ cur,
                           float* __restrict__ acc, const float* __restrict__ step_scale,
                           int step, int num_edges) {
    const float scale = step_scale[step];
    const int is64 = *flag;
    const int stride = gridDim.x * blockDim.x;
    for (int e = blockIdx.x * blockDim.x + threadIdx.x; e < num_edges; e += stride) {
        int src, dst;
        if (is64) {
            const long long* s = (const long long*)ei_raw;
            src = (int)s[e]; dst = (int)s[e + num_edges];
        } else {
            const int* s = (const int*)ei_raw;
            src = s[e]; dst = s[e + num_edges];
        }
        atomicAdd(&acc[dst], cur[src] * (probs[e] * scale));
    }
}

__global__ void k_node(float* __restrict__ cur, float* __restrict__ acc,
                       float* __restrict__ surv, const float* __restrict__ bias_p,
                       float* __restrict__ out, int n, int write_out) {
    int i = blockIdx.x * blockDim.x + threadIdx.x;
    if (i < n) {
        float c = acc[i] + bias_p[0];
        acc[i] = 0.0f;
        cur[i] = c;
        float s = surv[i] * (1.0f - c);
        surv[i] = s;
        if (write_out) out[i] = fminf(fmaxf(1.0f - s, 0.0f), 1.0f);
    }
}

static inline size_t al256(size_t x) { return (x + 255) & ~(size_t)255; }

extern "C" void kernel_launch(void* const* d_in, const int* in_sizes, int n_in,
                              void* d_out, int out_size, void* d_ws, size_t ws_size,
                              hipStream_t stream) {
    const float* x           = (const float*)d_in[0];
    const void*  ei          = d_in[1];
    const float* probs       = (const float*)d_in[2];
    const float* time_decay  = (const float*)d_in[3];
    const float* node_bias   = (const float*)d_in[4];
    const float* edge_weight = (const float*)d_in[5];
    float* outf = (float*)d_out;

    const int n = in_sizes[0];
    const int E = in_sizes[2];
    const int S = in_sizes[3];

    char* ws = (char*)d_ws;
    int*          flag       = (int*)ws;                      // 4B @ 0
    float*        step_scale = (float*)(ws + 64);             // S floats (S<=48)
    unsigned int* partials   = (unsigned int*)(ws + 256);     // <=256 u32 (scan)

    const int nbins_d  = (n + B2 - 1) >> SH2;
    const int nchunk   = nbins_d;                  // same 4096 granularity
    const int nbuckets = nbins_d * nchunk;
    const int pstride  = nbins_d << SH2;
    const int ntotal   = nbuckets * PB;
    const int scanB    = (ntotal + 1023) / 1024;

    const size_t off_ph   = 2560;
    const size_t ph_b     = (size_t)ntotal * 4;
    const size_t off_buf  = al256(off_ph + ph_b);
    const size_t nbA      = al256((size_t)n * 4);
    const size_t off_surv = off_buf + nbA;
    const size_t off_part = al256(off_surv + nbA);
    const size_t part_b   = (size_t)nchunk * pstride * 4;
    const size_t off_sort = al256(off_part + part_b);
    const size_t req      = off_sort + (size_t)E * 8;

    const int nthreads  = 256;
    const int node_grid = (n + nthreads - 1) / nthreads;

    const bool ok = (n <= (1 << 17)) && (nbuckets >= 1) && (nbuckets <= MAXB) &&
                    (S <= 48) && (scanB >= 1) && (scanB <= 256) &&
                    (E >= 64) && (ws_size >= req);

    k_detect<<<1, 64, 0, stream>>>((const unsigned long long*)ei, flag);
    k_scales<<<1, 64, 0, stream>>>(time_decay, edge_weight, step_scale, S);

    if (!ok) {
        // Raw-atomic fallback: cur | surv | acc.
        float* cur  = (float*)(ws + 2560);
        float* surv = (float*)(ws + 2560 + nbA);
        float* acc  = (float*)(ws + 2560 + 2 * nbA);
        k_init0<<<node_grid, nthreads, 0, stream>>>(x, cur, surv, acc, n);
        for (int s = 0; s < S; ++s) {
            k_edge_raw<<<2048, nthreads, 0, stream>>>(ei, flag, probs, cur, acc,
                                                      step_scale, s, E);
            k_node<<<node_grid, nthreads, 0, stream>>>(cur, acc, surv, node_bias,
                                                       outf, n, s == S - 1 ? 1 : 0);
        }
        return;
    }

    unsigned int* ph     = (unsigned int*)(ws + off_ph);
    float*        bufA   = (float*)(ws + off_buf);
    float*        surv   = (float*)(ws + off_surv);
    float*        part   = (float*)(ws + off_part);
    float2*       sorted = (float2*)(ws + off_sort);

    // cur ping-pong: last step (s=S-1) must READ a ws buffer.
    float* b0 = (S % 2 == 0) ? outf : bufA;   // cur_in for even s
    float* b1 = (S % 2 == 0) ? bufA : outf;   // cur_in for odd s

    k_init<<<node_grid, nthreads, 0, stream>>>(x, b0, surv, n);

    k_hist<<<PB, BT, 0, stream>>>(ei, flag, ph, E, nbuckets, nchunk);
    k_scan1<<<scanB, 1024, 0, stream>>>(ph, partials, ntotal);
    k_scan2<<<1, 1024, 0, stream>>>(partials, scanB);
    k_scan3<<<scanB, 1024, 0, stream>>>(ph, partials, ntotal);
    k_place<<<PB, BT, 0, stream>>>(ei, flag, probs, ph, sorted, E, nbuckets, nchunk);

    for (int s = 0; s < S; ++s) {
        float* ci = (s % 2 == 0) ? b0 : b1;
        float* co = (s % 2 == 0) ? b1 : b0;
        k_step<<<nbuckets, STEP_TPB, 0, stream>>>(sorted, ph, ci, part,
                                                  pstride, nbuckets, nchunk, n, E);
        k_reduce<<<node_grid, nthreads, 0, stream>>>(part, pstride, nchunk, co, surv,
                                                     step_scale, node_bias, outf,
                                                     s, n, s == S - 1 ? 1 : 0);
    }
}

// Round 11
// 695.645 us; speedup vs baseline: 1.2686x; 1.2686x over previous
//
#include <hip/hip_runtime.h>
#include <math.h>

// Graph-diffusion, 10 steps of edge-scatter + node update.
//
// R10 post-mortem: steps are NOT gather-limited (R10's zero-gather step ran
// at the same ~60us as R9's gather step). All step variants stream at only
// ~1.3TB/s: 8B loads + dependent per-edge chain + ~2 waves/SIMD = too little
// memory-level parallelism. R11 = R9's proven build (k_bucket, 99us,
// unchanged) + a step rebuilt for MLP/occupancy:
//   k_step: TPB 256, single 8KB LDS acc (random 2-way bank alias is free),
//           8 blocks/CU = 32 waves/CU (cap); splits=40 -> grid 1960, whole
//           grid resident in one round; 4 edges/thread/iter via 2x float4
//           (32B/lane in flight, 4 independent gathers + 4 LDS atomics).
//   k_reduce: 40-way partial sum + fused scale/bias/surv/clip.

#define MAXBINS     64
#define BIN_SHIFT   11
#define BIN_SIZE    2048      // 1 << BIN_SHIFT
#define STAGE_CAP   64        // LDS staging slots per bin (= wave width)
#define BUCKET_GRID 1024
#define BUCKET_TPB  256
#define BUCKET_K    8         // edges per thread per round
#define STEP_TPB    256

__global__ void k_detect(const unsigned long long* ei, int* flag) {
    if (blockIdx.x == 0 && threadIdx.x == 0) {
        // int64 indices (<2^17) have zero high words; int32 data read as u64
        // carries a random index in the high word (all-64-zero ~ never).
        int is64 = 1;
        for (int k = 0; k < 64; ++k)
            if ((ei[k] >> 32) != 0ULL) { is64 = 0; break; }
        *flag = is64;
    }
}

// scales + zero the global bucket cursors.
__global__ void k_scales(const float* __restrict__ time_decay,
                         const float* __restrict__ edge_weight,
                         float* __restrict__ step_scale, int num_steps,
                         unsigned int* __restrict__ gcur) {
    int i = threadIdx.x;
    if (i < num_steps) {
        float td = time_decay[i];
        step_scale[i] = edge_weight[i] * expf(-td * td);
    }
    if (i < MAXBINS) gcur[i] = 0u;
}

__global__ void k_init(const float* __restrict__ x, float* __restrict__ cur0,
                       float* __restrict__ surv, int n) {
    int i = blockIdx.x * blockDim.x + threadIdx.x;
    if (i < n) {
        float v = x[i];
        cur0[i] = v;
        surv[i] = 1.0f - v;
    }
}

// Single-pass bucketing: LDS staging, batched cursor reservation,
// per-wave-per-bin flush (unchanged from R9: proven, 99us).
__global__ void k_bucket(const void* __restrict__ ei_raw, const int* __restrict__ flag,
                         const float* __restrict__ probs, unsigned int* __restrict__ gcur,
                         float2* __restrict__ sorted, unsigned int capr,
                         int E, int nbins) {
    __shared__ float2 buf[MAXBINS][STAGE_CAP];
    __shared__ unsigned int cnt[MAXBINS];
    __shared__ unsigned int gbase[MAXBINS];
    const int t = threadIdx.x;
    const int wid = t >> 6, lane = t & 63;
    const int nwaves = BUCKET_TPB / 64;
    const int is64 = *flag;
    const int chunk = (E + gridDim.x - 1) / gridDim.x;
    const int beg = blockIdx.x * chunk;
    const int end = min(E, beg + chunk);
    for (int i = t; i < nbins; i += BUCKET_TPB) cnt[i] = 0u;
    __syncthreads();
    const int ROUND = BUCKET_TPB * BUCKET_K;
    for (int rbeg = beg; rbeg < end; rbeg += ROUND) {
        // ---- insert phase ----
        for (int k = 0; k < BUCKET_K; ++k) {
            int e = rbeg + k * BUCKET_TPB + t;
            if (e < end) {
                int src, dst;
                if (is64) {
                    const long long* s = (const long long*)ei_raw;
                    src = (int)s[e]; dst = (int)s[e + E];
                } else {
                    const int* s = (const int*)ei_raw;
                    src = s[e]; dst = s[e + E];
                }
                float pr = probs[e];
                int bin = dst >> BIN_SHIFT;
                unsigned int payload = (unsigned int)src |
                                       ((unsigned int)(dst & (BIN_SIZE - 1)) << 17);
                unsigned int pos = atomicAdd(&cnt[bin], 1u);
                if (pos < STAGE_CAP) {
                    buf[bin][pos] = make_float2(__uint_as_float(payload), pr);
                } else {
                    // rare overflow: direct per-edge reservation (guarded)
                    unsigned int gp = atomicAdd(&gcur[bin], 1u);
                    if (gp < capr)
                        sorted[(size_t)bin * capr + gp] =
                            make_float2(__uint_as_float(payload), pr);
                }
            }
        }
        __syncthreads();
        // ---- batched reservation: one thread per bin ----
        if (t < nbins) {
            unsigned int c = min(cnt[t], (unsigned int)STAGE_CAP);
            if (c > 0u) gbase[t] = atomicAdd(&gcur[t], c);
        }
        __syncthreads();
        // ---- flush: one bin per wave per iter; lane l writes element l ----
        for (int b = wid; b < nbins; b += nwaves) {
            unsigned int c = min(cnt[b], (unsigned int)STAGE_CAP);
            if ((unsigned int)lane < c) {
                unsigned int gp = gbase[b] + (unsigned int)lane;
                if (gp < capr)
                    sorted[(size_t)b * capr + gp] = buf[b][lane];
            }
        }
        __syncthreads();
        for (int i = t; i < nbins; i += BUCKET_TPB) cnt[i] = 0u;
        __syncthreads();
    }
}

// (bin, split) per block, 256 threads, 8KB LDS acc -> 8 blocks/CU (32 waves).
// 4 edges/thread/iter via 2x float4; sub-segment start rounded to 4 edges.
__global__ void __launch_bounds__(STEP_TPB)
k_step(const float2* __restrict__ sorted, const unsigned int* __restrict__ gcur,
       const float* __restrict__ cur_in, float* __restrict__ part,
       unsigned int capr, int pstride, int nbins, int splits) {
    __shared__ float acc[BIN_SIZE];
    const int bin = blockIdx.x / splits;
    const int sp  = blockIdx.x - bin * splits;
    const int t = threadIdx.x;
    for (int i = t; i < BIN_SIZE; i += STEP_TPB) acc[i] = 0.0f;
    __syncthreads();
    unsigned int cntv = min(gcur[bin], capr);
    unsigned int sub = ((cntv + (unsigned int)splits - 1) / (unsigned int)splits + 3u) & ~3u;
    unsigned int s0 = min(cntv, (unsigned int)sp * sub);
    unsigned int s1 = min(cntv, s0 + sub);
    const float2* base = sorted + (size_t)bin * capr;
    for (unsigned int j = s0 + (unsigned int)t * 4u; j < s1; j += STEP_TPB * 4u) {
        if (j + 4u <= s1) {                       // aligned: s0%4==0, j%4==0
            float4 a = *reinterpret_cast<const float4*>(base + j);
            float4 b = *reinterpret_cast<const float4*>(base + j + 2);
            unsigned int k0 = __float_as_uint(a.x), k1 = __float_as_uint(a.z);
            unsigned int k2 = __float_as_uint(b.x), k3 = __float_as_uint(b.z);
            float m0 = cur_in[k0 & 0x1FFFFu] * a.y;
            float m1 = cur_in[k1 & 0x1FFFFu] * a.w;
            float m2 = cur_in[k2 & 0x1FFFFu] * b.y;
            float m3 = cur_in[k3 & 0x1FFFFu] * b.w;
            atomicAdd(&acc[k0 >> 17], m0);
            atomicAdd(&acc[k1 >> 17], m1);
            atomicAdd(&acc[k2 >> 17], m2);
            atomicAdd(&acc[k3 >> 17], m3);
        } else {
            for (unsigned int q = j; q < s1; ++q) {
                float2 kp = base[q];
                unsigned int k = __float_as_uint(kp.x);
                atomicAdd(&acc[k >> 17], cur_in[k & 0x1FFFFu] * kp.y);
            }
        }
    }
    __syncthreads();
    float* dst = part + (size_t)sp * pstride + (size_t)bin * BIN_SIZE;
    for (int i = t; i < BIN_SIZE; i += STEP_TPB)
        dst[i] = acc[i];                          // unconditional (no poison left)
}

// Sum partials + fused scale/bias/surv/clip.
__global__ void k_reduce(const float* __restrict__ part, int pstride, int splits,
                         float* __restrict__ cur_out, float* __restrict__ surv,
                         const float* __restrict__ step_scale, const float* __restrict__ bias_p,
                         float* __restrict__ out, int step, int n, int last) {
    int i = blockIdx.x * blockDim.x + threadIdx.x;
    if (i >= n) return;
    float c = 0.0f;
    for (int s = 0; s < splits; ++s) c += part[(size_t)s * pstride + i];
    c = c * step_scale[step] + bias_p[0];
    if (!last) cur_out[i] = c;
    float sv = surv[i] * (1.0f - c);
    surv[i] = sv;
    if (last) out[i] = fminf(fmaxf(1.0f - sv, 0.0f), 1.0f);
}

// --- minimal fallback (ws too small / n too big; not expected) ---
__global__ void k_init0(const float* __restrict__ x, float* __restrict__ cur,
                        float* __restrict__ surv, float* __restrict__ acc, int n) {
    int i = blockIdx.x * blockDim.x + threadIdx.x;
    if (i < n) {
        float v = x[i];
        cur[i] = v; surv[i] = 1.0f - v; acc[i] = 0.0f;
    }
}

__global__ void k_edge_raw(const void* __restrict__ ei_raw, const int* __restrict__ flag,
                           const float* __restrict__ probs, const float* __restrict__ cur,
                           float* __restrict__ acc, const float* __restrict__ step_scale,
                           int step, int num_edges) {
    const float scale = step_scale[step];
    const int is64 = *flag;
    const int stride = gridDim.x * blockDim.x;
    for (int e = blockIdx.x * blockDim.x + threadIdx.x; e < num_edges; e += stride) {
        int src, dst;
        if (is64) {
            const long long* s = (const long long*)ei_raw;
            src = (int)s[e]; dst = (int)s[e + num_edges];
        } else {
            const int* s = (const int*)ei_raw;
            src = s[e]; dst = s[e + num_edges];
        }
        atomicAdd(&acc[dst], cur[src] * (probs[e] * scale));
    }
}

__global__ void k_node(float* __restrict__ cur, float* __restrict__ acc,
                       float* __restrict__ surv, const float* __restrict__ bias_p,
                       float* __restrict__ out, int n, int write_out) {
    int i = blockIdx.x * blockDim.x + threadIdx.x;
    if (i < n) {
        float c = acc[i] + bias_p[0];
        acc[i] = 0.0f;
        cur[i] = c;
        float s = surv[i] * (1.0f - c);
        surv[i] = s;
        if (write_out) out[i] = fminf(fmaxf(1.0f - s, 0.0f), 1.0f);
    }
}

static inline size_t al256(size_t x) { return (x + 255) & ~(size_t)255; }

extern "C" void kernel_launch(void* const* d_in, const int* in_sizes, int n_in,
                              void* d_out, int out_size, void* d_ws, size_t ws_size,
                              hipStream_t stream) {
    const float* x           = (const float*)d_in[0];
    const void*  ei          = d_in[1];
    const float* probs       = (const float*)d_in[2];
    const float* time_decay  = (const float*)d_in[3];
    const float* node_bias   = (const float*)d_in[4];
    const float* edge_weight = (const float*)d_in[5];
    float* outf = (float*)d_out;

    const int n = in_sizes[0];
    const int E = in_sizes[2];
    const int S = in_sizes[3];

    char* ws = (char*)d_ws;
    int*          flag       = (int*)ws;                    // 4B @ 0
    float*        step_scale = (float*)(ws + 64);           // S floats
    unsigned int* gcur       = (unsigned int*)(ws + 256);   // MAXBINS u32

    const int nbins   = (n + BIN_SIZE - 1) >> BIN_SHIFT;
    const int pstride = nbins * BIN_SIZE;

    // Bucket-region capacity: want mean+16sigma, accept down to mean+6sigma.
    const double   meand  = (double)E / (nbins > 0 ? nbins : 1);
    const double   sigma  = sqrt(meand > 1.0 ? meand : 1.0);
    unsigned int   want   = (unsigned int)(meand + 16.0 * sigma + 64.0);
    unsigned int   least  = (unsigned int)(meand + 6.0 * sigma + 64.0);
    want  = (want  + 63u) & ~63u;
    least = (least + 63u) & ~63u;

    const size_t nbA      = al256((size_t)n * 4);
    const size_t off_buf  = 512;
    const size_t off_surv = off_buf + nbA;
    const size_t off_part = al256(off_surv + nbA);

    // Choose largest SPLITS whose layout fits with capr >= least.
    int splits = 0;
    unsigned int capr = 0;
    size_t off_sort = 0;
    const int cand[5] = {40, 32, 24, 16, 8};
    for (int ci = 0; ci < 5; ++ci) {
        int sp = cand[ci];
        size_t part_b = (size_t)sp * pstride * 4;
        size_t osort  = al256(off_part + part_b);
        if (ws_size <= osort) continue;
        size_t availb = ws_size - osort;
        unsigned int acap = (unsigned int)((availb / ((size_t)nbins * 8)) & ~(size_t)63);
        if (acap >= least) {
            splits  = sp;
            capr    = acap < want ? acap : want;
            off_sort = osort;
            break;
        }
    }

    const int nthreads  = 256;
    const int node_grid = (n + nthreads - 1) / nthreads;

    const bool ok = (n <= (1 << 17)) && (nbins >= 1) && (nbins <= MAXBINS) &&
                    (E > 0) && (splits > 0);

    k_detect<<<1, 64, 0, stream>>>((const unsigned long long*)ei, flag);
    k_scales<<<1, 64, 0, stream>>>(time_decay, edge_weight, step_scale, S, gcur);

    if (!ok) {
        // Raw-atomic fallback: cur | surv | acc.
        float* cur  = (float*)(ws + off_buf);
        float* surv = (float*)(ws + off_surv);
        float* acc  = (float*)(ws + off_surv + nbA);
        k_init0<<<node_grid, nthreads, 0, stream>>>(x, cur, surv, acc, n);
        for (int s = 0; s < S; ++s) {
            k_edge_raw<<<2048, nthreads, 0, stream>>>(ei, flag, probs, cur, acc,
                                                      step_scale, s, E);
            k_node<<<node_grid, nthreads, 0, stream>>>(cur, acc, surv, node_bias,
                                                       outf, n, s == S - 1 ? 1 : 0);
        }
        return;
    }

    float*  bufA   = (float*)(ws + off_buf);
    float*  surv   = (float*)(ws + off_surv);
    float*  part   = (float*)(ws + off_part);
    float2* sorted = (float2*)(ws + off_sort);

    // cur ping-pong: last step (s=S-1) must READ a ws buffer.
    float* b0 = (S % 2 == 0) ? outf : bufA;   // cur_in for even s
    float* b1 = (S % 2 == 0) ? bufA : outf;   // cur_in for odd s

    k_init<<<node_grid, nthreads, 0, stream>>>(x, b0, surv, n);

    k_bucket<<<BUCKET_GRID, BUCKET_TPB, 0, stream>>>(ei, flag, probs, gcur, sorted,
                                                     capr, E, nbins);

    const int step_grid = nbins * splits;
    for (int s = 0; s < S; ++s) {
        float* ci = (s % 2 == 0) ? b0 : b1;
        float* co = (s % 2 == 0) ? b1 : b0;
        k_step<<<step_grid, STEP_TPB, 0, stream>>>(sorted, gcur, ci, part,
                                                   capr, pstride, nbins, splits);
        k_reduce<<<node_grid, nthreads, 0, stream>>>(part, pstride, splits, co, surv,
                                                     step_scale, node_bias, outf,
                                                     s, n, s == S - 1 ? 1 : 0);
    }
}